// Round 6
// baseline (248.154 us; speedup 1.0000x reference)
//
#include <hip/hip_runtime.h>
#include <hip/hip_bf16.h>
#include <math.h>

// Problem constants (match reference)
#define NNODES 50000
#define NEDGES 800000
#define INF 128
#define OUTF 128
#define HEADS 2
#define NEG_SLOPE 0.2f

// Padded-bin CSR: degree ~ Poisson(16); CAP=32 overflows on ~1e-4 of nodes;
// overflow edges go to a small exact-path list.
#define CAP 32
#define OVFCAP 32768

__device__ __forceinline__ unsigned short f2bf(float f) {
    unsigned u = __float_as_uint(f);
    unsigned r = (u + 0x7FFFu + ((u >> 16) & 1u)) >> 16;   // RNE
    return (unsigned short)r;
}
__device__ __forceinline__ float bf2f(unsigned short b) {
    return __uint_as_float((unsigned)b << 16);
}

typedef __attribute__((ext_vector_type(8))) short frag_ab;   // 8 bf16 (4 VGPRs)
typedef __attribute__((ext_vector_type(4))) float frag_cd;   // 4 fp32 acc
struct us8 { ushort4 a, b; };   // 8 halfs = 16 B

#define APITCH 136   // halfs per LDS K-major row (16B-aligned, odd bank stride)
#define EPITCH 68    // halfs per LDS epilogue row

// ---------- K0: prep — cursor init, W->bf16, wl/wr = W^T attn_{l,r} ----------
// el = feat @ (W^T attn_l): precomputing wl/wr removes el/er from the gemm.
__global__ __launch_bounds__(256) void prep(const float* __restrict__ W,
                                            const float* __restrict__ attn_l,
                                            const float* __restrict__ attn_r,
                                            int* cursor, int* ovfcnt,
                                            unsigned short* __restrict__ Wb,
                                            float* __restrict__ wl, float* __restrict__ wr,
                                            int N) {
    const int b = blockIdx.x, t = threadIdx.x;
    const int i = b * 256 + t;
    if (i < N) cursor[i] = 0;
    if (i == 0) *ovfcnt = 0;
    if (b < 32) {                      // W -> bf16: 8192 float4 groups
        int idx = b * 256 + t;
        float4 g = *(const float4*)(W + (size_t)idx * 4);
        ushort4 v; v.x = f2bf(g.x); v.y = f2bf(g.y); v.z = f2bf(g.z); v.w = f2bf(g.w);
        *(ushort4*)(Wb + (size_t)idx * 4) = v;
    } else if (b == 32) {              // wl[h*128+f] = sum_o attn_l[h,o] * W[h,o,f]
        int h = t >> 7, f = t & 127;
        float s = 0.f;
#pragma unroll 8
        for (int o = 0; o < 128; ++o)
            s += attn_l[h * 128 + o] * W[(size_t)(h * 128 + o) * 128 + f];
        wl[t] = s;
    } else if (b == 33) {
        int h = t >> 7, f = t & 127;
        float s = 0.f;
#pragma unroll 8
        for (int o = 0; o < 128; ++o)
            s += attn_r[h * 128 + o] * W[(size_t)(h * 128 + o) * 128 + f];
        wr[t] = s;
    }
}

// ---------- K1: MFMA gemm: ftb = bf16(feat @ Wcat^T) ----------
// Block = 4 waves. A (64 nodes x 128k bf16) staged once; B from pre-converted
// Wb per j-tile. C/D layout (m89/m91): col=lane&15, row=(lane>>4)*4+reg.
// Epilogue: C -> LDS (reusing Bsl) -> coalesced 16B stores (2 per lane).
__global__ __launch_bounds__(256) void gemm_mfma(const float* __restrict__ feat,
                                                 const unsigned short* __restrict__ Wb,
                                                 unsigned short* __restrict__ ftb,
                                                 int N) {
    __shared__ unsigned short Asl[64 * APITCH];
    __shared__ unsigned short Bsl[64 * APITCH];   // also the epilogue buffer
    const int t = threadIdx.x;
    const int n0 = blockIdx.x * 64;
    const int w = t >> 6, lane = t & 63;
    const int m16 = lane & 15, quad = lane >> 4;

    // stage A once: 64 rows x 128 k, fp32 -> bf16
#pragma unroll
    for (int i = 0; i < 8; ++i) {
        int q = t + i * 256;       // 0..2047
        int r = q >> 5;            // row 0..63
        int c4 = q & 31;           // float4 index 0..31
        int gn = n0 + r;
        float4 g = (gn < N) ? *(const float4*)(feat + (size_t)gn * INF + c4 * 4)
                            : make_float4(0.f, 0.f, 0.f, 0.f);
        ushort4 v; v.x = f2bf(g.x); v.y = f2bf(g.y); v.z = f2bf(g.z); v.w = f2bf(g.w);
        *(ushort4*)(&Asl[r * APITCH + c4 * 4]) = v;
    }

    const int arow = w * 16 + m16;

    for (int jt = 0; jt < 4; ++jt) {
        __syncthreads();   // A ready / previous epilogue reads done
        // stage B (64 j x 128 k) from bf16 Wb: 1024 ushort8 chunks
#pragma unroll
        for (int i = 0; i < 4; ++i) {
            int q = t + i * 256;
            int r = q >> 4;            // j-row 0..63
            int c8 = q & 15;           // ushort8 chunk 0..15
            us8 v = *(const us8*)(Wb + (size_t)(jt * 64 + r) * 128 + c8 * 8);
            *(us8*)(&Bsl[r * APITCH + c8 * 8]) = v;
        }
        __syncthreads();

        frag_cd acc[4];
#pragma unroll
        for (int nt = 0; nt < 4; ++nt) acc[nt] = frag_cd{0.f, 0.f, 0.f, 0.f};

#pragma unroll
        for (int kc = 0; kc < 4; ++kc) {
            frag_ab af = *(frag_ab*)(&Asl[arow * APITCH + kc * 32 + quad * 8]);
#pragma unroll
            for (int nt = 0; nt < 4; ++nt) {
                frag_ab bf = *(frag_ab*)(&Bsl[(nt * 16 + m16) * APITCH + kc * 32 + quad * 8]);
                acc[nt] = __builtin_amdgcn_mfma_f32_16x16x32_bf16(af, bf, acc[nt], 0, 0, 0);
            }
        }

        __syncthreads();   // everyone done reading Bsl -> reuse as epilogue buf
        // write C tiles (bf16) into per-wave LDS region: row-major 16 x 64
        unsigned short* ep = &Bsl[w * 16 * EPITCH];
#pragma unroll
        for (int nt = 0; nt < 4; ++nt) {
#pragma unroll
            for (int reg = 0; reg < 4; ++reg)
                ep[(quad * 4 + reg) * EPITCH + nt * 16 + m16] = f2bf(acc[nt][reg]);
        }
        // readback: each lane moves a full 16-half chunk (row r, cols c*16..c*16+15)
        // BUGFIX(r5): previously only the first 8 halfs of each chunk were copied.
        int r = lane >> 2;             // 0..15
        int c = lane & 3;              // chunk index 0..3
        us8 v0 = *(us8*)(&ep[r * EPITCH + c * 16]);
        us8 v1 = *(us8*)(&ep[r * EPITCH + c * 16 + 8]);
        int gm = n0 + w * 16 + r;
        if (gm < N) {
            *(us8*)(ftb + (size_t)gm * 256 + jt * 64 + c * 16) = v0;
            *(us8*)(ftb + (size_t)gm * 256 + jt * 64 + c * 16 + 8) = v1;
        }
    }
}

// ---------- K2: el/er per node from fp32 feat and wl/wr (exact logits) ----------
__global__ __launch_bounds__(256) void eler_kernel(const float* __restrict__ feat,
                                                   const float* __restrict__ wl,
                                                   const float* __restrict__ wr,
                                                   float2* __restrict__ el,
                                                   float2* __restrict__ er, int N) {
    __shared__ float swl[256], swr[256];
    const int t = threadIdx.x;
    swl[t] = wl[t];
    swr[t] = wr[t];
    __syncthreads();
    const int w = t >> 6, lane = t & 63;
    const int n = blockIdx.x * 4 + w;
    if (n >= N) return;
    float2 f = *(const float2*)(feat + (size_t)n * INF + lane * 2);
    float l0 = f.x * swl[lane * 2] + f.y * swl[lane * 2 + 1];
    float l1 = f.x * swl[128 + lane * 2] + f.y * swl[128 + lane * 2 + 1];
    float r0 = f.x * swr[lane * 2] + f.y * swr[lane * 2 + 1];
    float r1 = f.x * swr[128 + lane * 2] + f.y * swr[128 + lane * 2 + 1];
#pragma unroll
    for (int m = 1; m < 64; m <<= 1) {
        l0 += __shfl_xor(l0, m, 64);
        l1 += __shfl_xor(l1, m, 64);
        r0 += __shfl_xor(r0, m, 64);
        r1 += __shfl_xor(r1, m, 64);
    }
    if (lane == 0) {
        el[n] = make_float2(l0, l1);
        er[n] = make_float2(r0, r1);
    }
}

// ---------- K3: fused edge logits + leaky_relu + exp + padded-bin scatter ----------
// No segment-max (softmax shift-invariant; logits ~N(0,2), exp safe in fp32).
__global__ void edge_fused(const float2* __restrict__ el, const float2* __restrict__ er,
                           const float* __restrict__ e_w, const int* __restrict__ src,
                           const int* __restrict__ dst, const float* __restrict__ attn_ew,
                           int* __restrict__ cursor, int* __restrict__ ovfcnt,
                           uint2* __restrict__ edata, float4* __restrict__ ovf,
                           int E) {
    int e = blockIdx.x * 256 + threadIdx.x;
    if (e >= E) return;
    int s = src[e], d = dst[e];
    float2 ew2 = *(const float2*)(e_w + (size_t)e * 2);
    float2 elv = el[s];
    float2 erv = er[d];
    float v0 = elv.x + erv.x + ew2.x * attn_ew[0] + ew2.y * attn_ew[1];
    float v1 = elv.y + erv.y + ew2.x * attn_ew[2] + ew2.y * attn_ew[3];
    v0 = v0 >= 0.f ? v0 : NEG_SLOPE * v0;
    v1 = v1 >= 0.f ? v1 : NEG_SLOPE * v1;
    float ee0 = __expf(v0);
    float ee1 = __expf(v1);
    int pos = atomicAdd(cursor + d, 1);
    if (pos < CAP) {
        unsigned pk = ((unsigned)f2bf(ee1) << 16) | (unsigned)f2bf(ee0);
        edata[(size_t)d * CAP + pos] = make_uint2((unsigned)s, pk);
    } else {
        int o = atomicAdd(ovfcnt, 1);
        if (o < OVFCAP)
            ovf[o] = make_float4(__int_as_float(d), __int_as_float(s), ee0, ee1);
    }
}

// ---------- K4: wave-per-node gather-aggregate + normalize + residual + elu ----------
// Records bulk-loaded coalesced (lane l takes record l), then __shfl-broadcast
// per edge: removes the serialized wave-uniform L2 load from the dependent chain.
__global__ __launch_bounds__(256) void aggregate(const unsigned short* __restrict__ ftb,
                                                 const float* __restrict__ feat,
                                                 const uint2* __restrict__ edata,
                                                 const int* __restrict__ cursor,
                                                 const int* __restrict__ ovfcnt,
                                                 const float4* __restrict__ ovf,
                                                 float* __restrict__ out, int N) {
    const int t = threadIdx.x;
    const int w = t >> 6, l = t & 63;
    const int n = blockIdx.x * 4 + w;
    if (n >= N) return;
    const int c0 = 4 * l;            // this lane's 4 cols (0..252)
    const int h = l >> 5;            // lane's head
    const int cnt = cursor[n];
    const int cmain = cnt < CAP ? cnt : CAP;
    const uint2* eb = edata + (size_t)n * CAP;

    uint2 myrec = (l < cmain) ? eb[l] : make_uint2(0u, 0u);   // coalesced 256B

    float4 acc = make_float4(0.f, 0.f, 0.f, 0.f);
    float dn = 0.f;
#pragma unroll 4
    for (int i = 0; i < cmain; ++i) {
        int s = __shfl((int)myrec.x, i, 64);
        unsigned pk = (unsigned)__shfl((int)myrec.y, i, 64);
        float a = __uint_as_float(h ? (pk & 0xFFFF0000u) : (pk << 16));
        dn += a;
        uint2 v = *(const uint2*)(ftb + (size_t)s * 256 + c0);
        acc.x += a * __uint_as_float(v.x << 16);
        acc.y += a * __uint_as_float(v.x & 0xFFFF0000u);
        acc.z += a * __uint_as_float(v.y << 16);
        acc.w += a * __uint_as_float(v.y & 0xFFFF0000u);
    }
    if (cnt > CAP) {   // exact overflow path (rare)
        int no = *ovfcnt; if (no > OVFCAP) no = OVFCAP;
        for (int i = 0; i < no; ++i) {
            float4 ov = ovf[i];
            if (__float_as_int(ov.x) == n) {
                int s = __float_as_int(ov.y);
                float a = h ? ov.w : ov.z;
                dn += a;
                uint2 v = *(const uint2*)(ftb + (size_t)s * 256 + c0);
                acc.x += a * __uint_as_float(v.x << 16);
                acc.y += a * __uint_as_float(v.x & 0xFFFF0000u);
                acc.z += a * __uint_as_float(v.y << 16);
                acc.w += a * __uint_as_float(v.y & 0xFFFF0000u);
            }
        }
    }
    float inv = dn > 0.f ? 1.0f / dn : 0.f;
    float4 f4 = *(const float4*)(feat + (size_t)n * INF + (c0 & 127));
    float4 r;
    r.x = acc.x * inv + f4.x;
    r.y = acc.y * inv + f4.y;
    r.z = acc.z * inv + f4.z;
    r.w = acc.w * inv + f4.w;
    r.x = r.x > 0.f ? r.x : expm1f(r.x);
    r.y = r.y > 0.f ? r.y : expm1f(r.y);
    r.z = r.z > 0.f ? r.z : expm1f(r.z);
    r.w = r.w > 0.f ? r.w : expm1f(r.w);
    *(float4*)(out + (size_t)n * 256 + c0) = r;
}

extern "C" void kernel_launch(void* const* d_in, const int* in_sizes, int n_in,
                              void* d_out, int out_size, void* d_ws, size_t ws_size,
                              hipStream_t stream) {
    const float* feat    = (const float*)d_in[0];
    const float* e_w     = (const float*)d_in[1];
    const int*   src     = (const int*)d_in[2];
    const int*   dst     = (const int*)d_in[3];
    const float* W       = (const float*)d_in[4];
    const float* attn_l  = (const float*)d_in[5];
    const float* attn_r  = (const float*)d_in[6];
    const float* attn_ew = (const float*)d_in[7];
    float* out = (float*)d_out;

    const int N = in_sizes[0] / INF;   // 50000
    const int E = in_sizes[2];         // 800000

    // workspace carve-up (all offsets 16B-aligned for these sizes)
    unsigned short* ftb = (unsigned short*)d_ws;                 // N*256 bf16   (25.6 MB)
    uint2*  edata  = (uint2*)(ftb + (size_t)N * 256);            // N*CAP        (12.8 MB)
    float2* el     = (float2*)(edata + (size_t)N * CAP);         // N            (0.4 MB)
    float2* er     = el + N;                                     // N            (0.4 MB)
    unsigned short* Wb = (unsigned short*)(er + N);              // 32768 bf16
    float*  wl     = (float*)(Wb + 32768);                       // 256
    float*  wr     = wl + 256;                                   // 256
    float4* ovf    = (float4*)(wr + 256);                        // OVFCAP       (0.5 MB)
    int*    cursor = (int*)(ovf + OVFCAP);                       // N
    int*    ovfcnt = cursor + N;                                 // 1

    int pgrid = (N + 255) / 256; if (pgrid < 34) pgrid = 34;
    prep<<<pgrid, 256, 0, stream>>>(W, attn_l, attn_r, cursor, ovfcnt, Wb, wl, wr, N);

    gemm_mfma<<<(N + 63) / 64, 256, 0, stream>>>(feat, Wb, ftb, N);

    eler_kernel<<<(N + 3) / 4, 256, 0, stream>>>(feat, wl, wr, el, er, N);

    edge_fused<<<(E + 255) / 256, 256, 0, stream>>>(el, er, e_w, src, dst, attn_ew,
                                                    cursor, ovfcnt, edata, ovf, E);

    aggregate<<<(N + 3) / 4, 256, 0, stream>>>(ftb, feat, edata, cursor, ovfcnt, ovf, out, N);
}